// Round 5
// baseline (74.134 us; speedup 1.0000x reference)
//
#include <hip/hip_runtime.h>

// ---------------------------------------------------------------------------
// QConv2d collapses algebraically:
//   U = u0 (x) V  (wire 0 = MSB); <psi| sigma (x) I8 |psi> with psi = U P a
//   (a real, P = CNOT-ring perm) = alpha*c00 + beta*c11 + gamma*c01 per
//   (kernel k, pauli o), where c00/c11/c01 are quadratic reductions over the
//   16 raw patch pixels with the ring perm folded in at compile time, and
//   a = p/||p|| so divide by n = ||p||^2.
// This round: 4 patches per thread (same batch) to amortize the 36 scoef
// LDS reads + setup; stores remain lane-coalesced along l.
// ---------------------------------------------------------------------------

struct cplx { float re, im; };
__device__ inline cplx cmul(cplx a, cplx b){ return {a.re*b.re - a.im*b.im, a.re*b.im + a.im*b.re}; }
__device__ inline cplx cconj(cplx a){ return {a.re, -a.im}; }
__device__ inline cplx cadd(cplx a, cplx b){ return {a.re+b.re, a.im+b.im}; }

// CNOT ring map on basis index (wire 0 = MSB), exactly mirrors reference.
__host__ __device__ constexpr int ringf(int i){
    int s = i;
    for (int w = 0; w < 4; ++w){
        int c = w, t = (w + 1) & 3;
        if ((s >> (3 - c)) & 1) s ^= 1 << (3 - t);
    }
    return s;
}

// 241 thread-groups per batch; each thread does l = 4g .. 4g+3 (last: l=960).
__global__ __launch_bounds__(256) void qconv_kernel(
    const float* __restrict__ x, const float* __restrict__ w,
    float* __restrict__ out, int B)
{
    __shared__ float scoef[36];
    {
        int t = threadIdx.x;
        if (t < 12) {
            int k = t / 3, o = t - 3 * (t / 3);
            float th = w[k*12 + 0], ph = w[k*12 + 1], om = w[k*12 + 2];
            float c = cosf(th * 0.5f), s = sinf(th * 0.5f);
            cplx u[2][2];
            u[0][0] = { c, 0.f };
            u[0][1] = { -cosf(om) * s, -sinf(om) * s };
            u[1][0] = {  cosf(ph) * s,  sinf(ph) * s };
            u[1][1] = {  cosf(ph + om) * c, sinf(ph + om) * c };
            cplx sig[2][2];
            if (o == 0){      sig[0][0]={0,0}; sig[0][1]={1,0};  sig[1][0]={1,0}; sig[1][1]={0,0}; }   // X
            else if (o == 1){ sig[0][0]={0,0}; sig[0][1]={0,-1}; sig[1][0]={0,1}; sig[1][1]={0,0}; }   // Y
            else {            sig[0][0]={1,0}; sig[0][1]={0,0};  sig[1][0]={0,0}; sig[1][1]={-1,0}; }  // Z
            cplx A[2][2];
            #pragma unroll
            for (int a = 0; a < 2; ++a)
                #pragma unroll
                for (int b = 0; b < 2; ++b){
                    cplx acc = {0.f, 0.f};
                    #pragma unroll
                    for (int ss = 0; ss < 2; ++ss)
                        #pragma unroll
                        for (int tt = 0; tt < 2; ++tt)
                            acc = cadd(acc, cmul(cmul(cconj(u[ss][a]), sig[ss][tt]), u[tt][b]));
                    A[a][b] = acc;
                }
            scoef[t*3 + 0] = A[0][0].re;
            scoef[t*3 + 1] = A[1][1].re;
            scoef[t*3 + 2] = 2.f * A[0][1].re;
        }
    }
    __syncthreads();

    int gid = blockIdx.x * 256 + threadIdx.x;
    int b   = gid / 241;
    int g   = gid - b * 241;
    if (b >= B) return;
    int l0 = g * 4;

    const float* xb = x + (size_t)b * 4096;
    float n00[4], n11[4], n01[4];

    #pragma unroll
    for (int q = 0; q < 4; ++q){
        int l = l0 + q;
        n00[q] = 0.f; n11[q] = 0.f; n01[q] = 0.f;
        if (l < 961){
            int ho = l / 31;
            int wo = l - ho * 31;
            const float* src = xb + ho * 128 + wo * 2;
            float p[16];
            #pragma unroll
            for (int r = 0; r < 4; ++r){
                float2 v0 = *reinterpret_cast<const float2*>(src + r * 64);
                float2 v1 = *reinterpret_cast<const float2*>(src + r * 64 + 2);
                p[r*4+0] = v0.x; p[r*4+1] = v0.y; p[r*4+2] = v1.x; p[r*4+3] = v1.y;
            }
            float c00 = 0.f, c11 = 0.f, c01 = 0.f;
            #pragma unroll
            for (int i = 0; i < 16; ++i){
                float sq = p[i] * p[i];
                if (ringf(i) < 8){
                    c00 += sq;
                    #pragma unroll
                    for (int j = 0; j < 16; ++j)
                        if (ringf(j) == ringf(i) + 8) c01 += p[i] * p[j];
                } else {
                    c11 += sq;
                }
            }
            float inv = 1.0f / (c00 + c11);
            n00[q] = c00 * inv; n11[q] = c11 * inv; n01[q] = c01 * inv;
        }
    }

    float* dst = out + (size_t)b * 11532 + l0;   // 11532 = 12*961
    #pragma unroll
    for (int j = 0; j < 12; ++j){
        float ca = scoef[j*3+0], cb = scoef[j*3+1], cc = scoef[j*3+2];
        #pragma unroll
        for (int q = 0; q < 4; ++q){
            if (l0 + q < 961)
                dst[j*961 + q] = ca * n00[q] + cb * n11[q] + cc * n01[q];
        }
    }
}

extern "C" void kernel_launch(void* const* d_in, const int* in_sizes, int n_in,
                              void* d_out, int out_size, void* d_ws, size_t ws_size,
                              hipStream_t stream)
{
    const float* x = (const float*)d_in[0];   // (B,1,64,64) f32
    const float* w = (const float*)d_in[1];   // (4,4,3) f32
    float* out = (float*)d_out;               // (B,12,31,31) f32

    int B = in_sizes[0] / 4096;
    int total = B * 241;                      // thread-groups (4 patches each)
    int blocks = (total + 255) / 256;
    qconv_kernel<<<blocks, 256, 0, stream>>>(x, w, out, B);
}